// Round 4
// baseline (570.431 us; speedup 1.0000x reference)
//
#include <hip/hip_runtime.h>
#include <hip/hip_bf16.h>

#define KP    32
#define NIN_  64
#define RNK   16
#define NOUT_ 128
#define HID_  64
#define CDIM  1024   // RNK*NIN_
#define EPS_  1e-7f
#define LNEPS 1e-5f
#define NTOT  16384  // B*N

using short8 = __attribute__((ext_vector_type(8))) short;
using f32x4  = __attribute__((ext_vector_type(4))) float;

#define GLD16(gsrc, ldst) __builtin_amdgcn_global_load_lds( \
    (const __attribute__((address_space(1))) void*)(gsrc),  \
    (__attribute__((address_space(3))) void*)(ldst), 16, 0, 0)

__device__ __forceinline__ unsigned short f2bf(float x) {
  unsigned u = __float_as_uint(x);
  return (unsigned short)((u + 0x7fffu + ((u >> 16) & 1u)) >> 16);
}

// ---------------- prep: woT[n][k] = bf16(wo[k][n]) ----------------
__global__ __launch_bounds__(256) void k0_woT(const float* __restrict__ wo,
                                              unsigned short* __restrict__ woT) {
  __shared__ unsigned short S[64][129];
  const int t = threadIdx.x;
  const int k0 = blockIdx.x * 64;
  #pragma unroll
  for (int i = 0; i < 32; ++i) {
    const int idx = i * 256 + t;
    const int k = idx >> 7, n = idx & 127;
    S[k][n] = f2bf(wo[(long)(k0 + k) * NOUT_ + n]);
  }
  __syncthreads();
  #pragma unroll
  for (int i = 0; i < 32; ++i) {
    const int idx = i * 256 + t;
    const int n = idx >> 6, k = idx & 63;
    woT[(long)n * CDIM + k0 + k] = S[k][n];
  }
}

// ---------------- k1: wave-synchronous per-point pipeline -> A (bf16) -------
// 256 thr = 4 waves; each wave does 2 points (grid 2048). No feat staging:
// phase D reads feat straight from global (L1-dedup); LDS ~15 KB.
// Lane layout A-C: lane = 2*k + hh; lane layout D: rr = lane&15, riq = lane>>4.
__global__ __launch_bounds__(256) void k1_contract(
    const float* __restrict__ fp,   // (NTOT, KP, 3)
    const float* __restrict__ feat, // (NTOT, KP, NIN_)
    const float* __restrict__ ep,   // (NTOT, 3)
    const float* __restrict__ w1,   // (8, HID_)
    const float* __restrict__ b1, const float* __restrict__ g1,
    const float* __restrict__ be1,
    const float* __restrict__ w2,   // (HID_, RNK)
    const float* __restrict__ b2,
    unsigned short* __restrict__ A) // (NTOT, CDIM) bf16
{
  __shared__ float w1T[64][8];           // w1T[h][x] = w1[x][h]
  __shared__ float w2S[64][16];
  __shared__ float b1S[64], g1S[64], beS[64], b2S[16];
  __shared__ float kernS[4][KP][17];     // pad 17 -> conflict-free scalar reads

  const int t = threadIdx.x;
  const int wv = t >> 6, lane = t & 63;
  const int hh = lane & 1, kk = lane >> 1;

  if (t < 64) {
    #pragma unroll
    for (int x = 0; x < 8; ++x) w1T[t][x] = w1[x * HID_ + t];
    b1S[t] = b1[t]; g1S[t] = g1[t]; beS[t] = be1[t];
  }
  reinterpret_cast<float4*>(&w2S[0][0])[t] = reinterpret_cast<const float4*>(w2)[t];
  if (t < 16) b2S[t] = b2[t];
  __syncthreads();

  #pragma unroll 1
  for (int pi = 0; pi < 2; ++pi) {
    const long pt = (long)blockIdx.x * 8 + wv * 2 + pi;

    // ---- phase A: geometry for neighbor kk ----
    const float* prp = fp + (pt * KP + kk) * 3;
    const float prx = prp[0], pry = prp[1], prz = prp[2];
    const float* psp = ep + pt * 3;
    const float psx = psp[0], psy = psp[1], psz = psp[2];

    float sx = prx, sy = pry, sz = prz;
    #pragma unroll
    for (int m = 2; m <= 32; m <<= 1) {
      sx += __shfl_xor(sx, m); sy += __shfl_xor(sy, m); sz += __shfl_xor(sz, m);
    }
    const float inv = 1.f / 32.f;
    const float mx = sx * inv, my = sy * inv, mz = sz * inv;

    const float l1x = mx - prx, l1y = my - pry, l1z = mz - prz;
    const float l2x = prx - psx, l2y = pry - psy, l2z = prz - psz;
    const float l3x = psx - mx, l3y = psy - my, l3z = psz - mz;
    const float l1n = sqrtf(l1x * l1x + l1y * l1y + l1z * l1z);
    const float l2n = sqrtf(l2x * l2x + l2y * l2y + l2z * l2z);
    const float l3n = sqrtf(l3x * l3x + l3y * l3y + l3z * l3z);
    const float th1 = (l1x * l2x + l1y * l2y + l1z * l2z) / (l1n * l2n + EPS_);
    const float th2 = (l2x * l3x + l2y * l3y + l2z * l3z) / (l2n * l3n + EPS_);
    const float th3 = (l3x * l1x + l3y * l1y + l3z * l1z) / (l3n * l1n + EPS_);
    const float hn  = sqrtf(prx * prx + pry * pry + prz * prz);
    const float psn = sqrtf(psx * psx + psy * psy + psz * psz);
    float c = (psx * prx + psy * pry + psz * prz) / (psn * hn);
    c = fminf(1.f, fmaxf(-1.f, c));
    const float ri0 = acosf(c) * 0.31830988618379067f;
    const float ri1 = hn,  ri2 = l1n, ri3 = l2n;
    const float ri4 = l3n, ri5 = th1, ri6 = th2, ri7 = th3;

    // ---- phase B: vals = (ri @ w1 + b1), LN over 64 via lane-pair ----
    float vals[32];
    #pragma unroll
    for (int j = 0; j < 32; ++j) {
      const int h = hh * 32 + j;
      const float4 wa = *reinterpret_cast<const float4*>(&w1T[h][0]);
      const float4 wb = *reinterpret_cast<const float4*>(&w1T[h][4]);
      vals[j] = b1S[h]
        + ri0 * wa.x + ri1 * wa.y + ri2 * wa.z + ri3 * wa.w
        + ri4 * wb.x + ri5 * wb.y + ri6 * wb.z + ri7 * wb.w;
    }
    float s = 0.f;
    #pragma unroll
    for (int j = 0; j < 32; ++j) s += vals[j];
    s += __shfl_xor(s, 1);
    const float mu = s * (1.f / 64.f);
    float v2 = 0.f;
    #pragma unroll
    for (int j = 0; j < 32; ++j) { const float d = vals[j] - mu; v2 += d * d; }
    v2 += __shfl_xor(v2, 1);
    const float rstd = rsqrtf(v2 * (1.f / 64.f) + LNEPS);
    #pragma unroll
    for (int j = 0; j < 32; ++j) {
      const int h = hh * 32 + j;
      vals[j] = fmaxf((vals[j] - mu) * rstd * g1S[h] + beS[h], 0.f);
    }

    // ---- phase C: kern[r] = b2[r] + sum_h hdn[h]*w2[h][r] ----
    float kern[16];
    #pragma unroll
    for (int r = 0; r < 16; ++r) kern[r] = 0.f;
    #pragma unroll
    for (int j = 0; j < 32; ++j) {
      const int h = hh * 32 + j;
      const float hv = vals[j];
      #pragma unroll
      for (int rc = 0; rc < 4; ++rc) {
        const float4 wr = *reinterpret_cast<const float4*>(&w2S[h][rc * 4]);
        kern[rc * 4 + 0] += hv * wr.x;
        kern[rc * 4 + 1] += hv * wr.y;
        kern[rc * 4 + 2] += hv * wr.z;
        kern[rc * 4 + 3] += hv * wr.w;
      }
    }
    #pragma unroll
    for (int r = 0; r < 16; ++r) kern[r] += __shfl_xor(kern[r], 1);
    #pragma unroll
    for (int q = 0; q < 8; ++q)
      kernS[wv][kk][hh * 8 + q] = kern[hh * 8 + q] + b2S[hh * 8 + q];

    // ---- phase D: cont[r][i] = sum_k kern[k][r]*feat[k][i], feat from global
    const int rr = lane & 15, riq = lane >> 4;
    const float* fbase = feat + pt * (KP * NIN_) + riq * 4;
    f32x4 a0 = {0.f,0.f,0.f,0.f}, a1 = a0, a2 = a0, a3 = a0;
    #pragma unroll 8
    for (int kq = 0; kq < 32; ++kq) {
      const float kv = kernS[wv][kq][rr];
      const float* fb = fbase + kq * 64;
      const f32x4 f0 = *reinterpret_cast<const f32x4*>(fb);
      const f32x4 f1 = *reinterpret_cast<const f32x4*>(fb + 16);
      const f32x4 f2 = *reinterpret_cast<const f32x4*>(fb + 32);
      const f32x4 f3 = *reinterpret_cast<const f32x4*>(fb + 48);
      a0 += kv * f0; a1 += kv * f1; a2 += kv * f2; a3 += kv * f3;
    }
    unsigned short* Ap = A + pt * CDIM + rr * 64 + riq * 4;
    *reinterpret_cast<ushort4*>(Ap +  0) = make_ushort4(f2bf(a0[0]), f2bf(a0[1]), f2bf(a0[2]), f2bf(a0[3]));
    *reinterpret_cast<ushort4*>(Ap + 16) = make_ushort4(f2bf(a1[0]), f2bf(a1[1]), f2bf(a1[2]), f2bf(a1[3]));
    *reinterpret_cast<ushort4*>(Ap + 32) = make_ushort4(f2bf(a2[0]), f2bf(a2[1]), f2bf(a2[2]), f2bf(a2[3]));
    *reinterpret_cast<ushort4*>(Ap + 48) = make_ushort4(f2bf(a3[0]), f2bf(a3[1]), f2bf(a3[2]), f2bf(a3[3]));
  }
}

// ---------------- k2: bf16 MFMA GEMM + bias + LN; BM=16, grid=1024 ----------
// 4 waves; wave w owns n-cols [w*32, w*32+32). LDS 36 KB -> 4 blocks/CU.
__global__ __launch_bounds__(256) void k2_gemm_ln(
    const unsigned short* __restrict__ A,    // (NTOT, CDIM) bf16
    const unsigned short* __restrict__ woT,  // (NOUT_, CDIM) bf16
    const float* __restrict__ bwo, const float* __restrict__ gln,
    const float* __restrict__ bln, float* __restrict__ out)
{
  __shared__ __align__(16) char smem[36864];
  unsigned short* AsB = reinterpret_cast<unsigned short*>(smem);          // [2][16*64]
  unsigned short* BsB = reinterpret_cast<unsigned short*>(smem + 4096);   // [2][128*64]
  float* Cs = reinterpret_cast<float*>(smem);  // epilogue overlay [16][132]

  const int t = threadIdx.x;
  const int w = t >> 6, l = t & 63;
  const long row0 = (long)blockIdx.x * 16;

  f32x4 acc[2];
  acc[0] = (f32x4){0.f, 0.f, 0.f, 0.f};
  acc[1] = (f32x4){0.f, 0.f, 0.f, 0.f};

  auto stage = [&](int buf, int k0) {
    if (t < 128) {                      // A: 16 rows x 64 k = 128 x 16B
      const int row = t >> 3, c = t & 7;
      const int cs = c ^ (row & 7);
      GLD16(A + (row0 + row) * CDIM + k0 + cs * 8, AsB + buf * 1024 + t * 8);
    }
    unsigned short* Bd = BsB + buf * 8192;
    #pragma unroll
    for (int i = 0; i < 4; ++i) {       // B: 128 n-rows x 64 k
      const int idx = t + 256 * i;
      const int row = idx >> 3, c = idx & 7;
      const int cs = c ^ (row & 7);
      GLD16(woT + (long)row * CDIM + k0 + cs * 8, Bd + idx * 8);
    }
  };

  stage(0, 0);
  asm volatile("s_waitcnt vmcnt(0)" ::: "memory");
  __builtin_amdgcn_s_barrier();

  for (int c = 0; c < 16; ++c) {
    const int cur = c & 1;
    if (c < 15) stage(cur ^ 1, (c + 1) * 64);

    const unsigned short* Ab = AsB + cur * 1024;
    const unsigned short* Bb = BsB + cur * 8192;
    const int kg = l >> 4, m = l & 15;
    #pragma unroll
    for (int ks = 0; ks < 2; ++ks) {
      const int kc = ks * 4 + kg;
      const short8 af = *reinterpret_cast<const short8*>(&Ab[m * 64 + ((kc ^ (m & 7)) << 3)]);
      #pragma unroll
      for (int nt = 0; nt < 2; ++nt) {
        const int row = w * 32 + nt * 16 + m;
        const short8 bf = *reinterpret_cast<const short8*>(&Bb[row * 64 + ((kc ^ (row & 7)) << 3)]);
        acc[nt] = __builtin_amdgcn_mfma_f32_16x16x32_bf16(af, bf, acc[nt], 0, 0, 0);
      }
    }
    asm volatile("s_waitcnt vmcnt(0)" ::: "memory");
    __builtin_amdgcn_s_barrier();
  }

  // epilogue: scatter acc -> Cs (C/D layout: col=lane&15, row=(lane>>4)*4+r)
  #pragma unroll
  for (int nt = 0; nt < 2; ++nt)
    #pragma unroll
    for (int r = 0; r < 4; ++r) {
      const int row = (l >> 4) * 4 + r;
      const int col = w * 32 + nt * 16 + (l & 15);
      Cs[row * 132 + col] = acc[nt][r];
    }
  __syncthreads();

  // LN over 128 cols: 16 threads per row (t>>4 = row, t&15 -> 8 cols each)
  {
    const int row = t >> 4, q = t & 15;
    float4 v[2];
    #pragma unroll
    for (int i = 0; i < 2; ++i) {
      const float4 cv = *reinterpret_cast<const float4*>(&Cs[row * 132 + q * 8 + i * 4]);
      const float4 bv = *reinterpret_cast<const float4*>(&bwo[q * 8 + i * 4]);
      v[i] = make_float4(cv.x + bv.x, cv.y + bv.y, cv.z + bv.z, cv.w + bv.w);
    }
    float s = v[0].x + v[0].y + v[0].z + v[0].w + v[1].x + v[1].y + v[1].z + v[1].w;
    s += __shfl_xor(s, 1); s += __shfl_xor(s, 2);
    s += __shfl_xor(s, 4); s += __shfl_xor(s, 8);
    const float mu = s * (1.f / 128.f);
    float d2 = 0.f;
    #pragma unroll
    for (int i = 0; i < 2; ++i) {
      const float dx = v[i].x - mu, dy = v[i].y - mu, dz = v[i].z - mu, dw = v[i].w - mu;
      d2 += dx * dx + dy * dy + dz * dz + dw * dw;
    }
    d2 += __shfl_xor(d2, 1); d2 += __shfl_xor(d2, 2);
    d2 += __shfl_xor(d2, 4); d2 += __shfl_xor(d2, 8);
    const float rstd = rsqrtf(d2 * (1.f / 128.f) + LNEPS);
    float* op = out + (row0 + row) * NOUT_ + q * 8;
    #pragma unroll
    for (int i = 0; i < 2; ++i) {
      const float4 gv = *reinterpret_cast<const float4*>(&gln[q * 8 + i * 4]);
      const float4 bv = *reinterpret_cast<const float4*>(&bln[q * 8 + i * 4]);
      float4 o;
      o.x = (v[i].x - mu) * rstd * gv.x + bv.x;
      o.y = (v[i].y - mu) * rstd * gv.y + bv.y;
      o.z = (v[i].z - mu) * rstd * gv.z + bv.z;
      o.w = (v[i].w - mu) * rstd * gv.w + bv.w;
      *reinterpret_cast<float4*>(op + i * 4) = o;
    }
  }
}

extern "C" void kernel_launch(void* const* d_in, const int* in_sizes, int n_in,
                              void* d_out, int out_size, void* d_ws, size_t ws_size,
                              hipStream_t stream) {
  const float* fp   = (const float*)d_in[0];
  const float* feat = (const float*)d_in[1];
  const float* ep   = (const float*)d_in[2];
  const float* w1   = (const float*)d_in[3];
  const float* b1   = (const float*)d_in[4];
  const float* g1   = (const float*)d_in[5];
  const float* be1  = (const float*)d_in[6];
  const float* w2   = (const float*)d_in[7];
  const float* b2   = (const float*)d_in[8];
  const float* wo   = (const float*)d_in[9];
  const float* bwo  = (const float*)d_in[10];
  const float* gln  = (const float*)d_in[11];
  const float* bln  = (const float*)d_in[12];
  float* out = (float*)d_out;

  unsigned short* A   = (unsigned short*)d_ws;                          // 33.5 MB bf16
  unsigned short* woT = (unsigned short*)((char*)d_ws + (48u << 20));   // 256 KB bf16

  k0_woT<<<16, 256, 0, stream>>>(wo, woT);
  k1_contract<<<2048, 256, 0, stream>>>(fp, feat, ep, w1, b1, g1, be1, w2, b2, A);
  k2_gemm_ln<<<1024, 256, 0, stream>>>(A, woT, bwo, gln, bln, out);
}